// Round 3
// baseline (547.940 us; speedup 1.0000x reference)
//
#include <hip/hip_runtime.h>

// R10: fused single-wave scan. No producers, no LDS, no flags, no barriers.
// Each wave owns ROWS=4 rows (lanes 0..3); per group of 8 steps it loads
// lstm4 (8x float4) + x (2x float4) directly from global into registers
// (3-group-deep rotation E/O/F), does the staging math + recurrence
// in-register, and stores 2x float4 to out. 1024 blocks x 64 threads
// = 4 waves/CU, one per SIMD.
// Step math verbatim from R4-R9 (bit-exact):
//   L1 = m_lo*x + m_lo*c_lo ; c1 = (p^s1m) >= (L1^s1m)
//   c2 = ((p^f2m) - a3f) >= a4f
//   p  = c2 ? (c1 ? V11 : V01) : (c1 ? L1 : p)

#define NG 256   // T/8 groups of 8 steps
#define ROWS 4

__global__ __launch_bounds__(64) void fused_scan(
    const float* __restrict__ x, const float* __restrict__ p0,
    const float4* __restrict__ lstm4, float* __restrict__ out,
    int B, int T) {
#pragma clang fp contract(off)
  const int lane = threadIdx.x;
  if (lane >= ROWS) return;
  const size_t row = (size_t)blockIdx.x * ROWS + lane;
  const size_t rbase = row * (size_t)T;
  const float4* lp = lstm4 + rbase;                                // 8/group
  const float4* xp = reinterpret_cast<const float4*>(x + rbase);   // 2/group
  float4* op = reinterpret_cast<float4*>(out + rbase);             // 2/group
  float p = p0[row];

  // 3-deep register rotation: group g uses buffer g%3 (0=E,1=O,2=F);
  // body g prefetches g+2 into buffer (g+2)%3 == (g-1)%3 (free since g-1 done).
  float4 L0E, L1E, L2E, L3E, L4E, L5E, L6E, L7E, X0E, X1E;
  float4 L0O, L1O, L2O, L3O, L4O, L5O, L6O, L7O, X0O, X1O;
  float4 L0F, L1F, L2F, L3F, L4F, L5F, L6F, L7F, X0F, X1F;

#define LOADG(S, G)                                                     \
  {                                                                     \
    const float4* lb = lp + 8 * (G);                                    \
    L0##S = lb[0]; L1##S = lb[1]; L2##S = lb[2]; L3##S = lb[3];         \
    L4##S = lb[4]; L5##S = lb[5]; L6##S = lb[6]; L7##S = lb[7];         \
    X0##S = xp[2 * (G)];                                                \
    X1##S = xp[2 * (G) + 1];                                            \
  }

#define STEP(WV, XV, OV)                                                \
  {                                                                     \
    float4 wv = WV; /* (m_lo, m_up, c_lo, c_up) */                      \
    float xv = XV;                                                      \
    float a1 = wv.x * xv, a2 = wv.x * wv.z;                             \
    float L1v = a1 + a2;                                                \
    unsigned s1m = __float_as_uint(wv.x) & 0x80000000u;                 \
    float L1f = __uint_as_float(__float_as_uint(L1v) ^ s1m);            \
    float a3 = wv.y * xv, a4 = wv.y * wv.w;                             \
    unsigned f2m = (__float_as_uint(wv.y) & 0x80000000u) ^ 0x80000000u; \
    float a3f = __uint_as_float(__float_as_uint(a3) ^ f2m);             \
    float a4f = __uint_as_float(__float_as_uint(a4) ^ f2m);             \
    float V01 = a3 + a4;                                                \
    float V11 = (L1v + a3) + a4;                                        \
    unsigned pu = __float_as_uint(p);                                   \
    float pf = __uint_as_float(pu ^ s1m);                               \
    bool c1 = pf >= L1f;                                                \
    float pp = __uint_as_float(pu ^ f2m);                               \
    float qv = pp - a3f;                                                \
    bool c2 = qv >= a4f;                                                \
    float i1 = c1 ? V11 : V01;                                          \
    float i2 = c1 ? L1v : p;                                            \
    p = c2 ? i1 : i2;                                                   \
    OV = p;                                                             \
  }

#define BODY(CUR, PRE, G)                                               \
  {                                                                     \
    int pg = (G) + 2;                                                   \
    pg = (pg > NG - 1) ? (NG - 1) : pg;                                 \
    LOADG(PRE, pg)                                                      \
    float4 ov0, ov1;                                                    \
    STEP(L0##CUR, X0##CUR.x, ov0.x)                                     \
    STEP(L1##CUR, X0##CUR.y, ov0.y)                                     \
    STEP(L2##CUR, X0##CUR.z, ov0.z)                                     \
    STEP(L3##CUR, X0##CUR.w, ov0.w)                                     \
    STEP(L4##CUR, X1##CUR.x, ov1.x)                                     \
    STEP(L5##CUR, X1##CUR.y, ov1.y)                                     \
    STEP(L6##CUR, X1##CUR.z, ov1.z)                                     \
    STEP(L7##CUR, X1##CUR.w, ov1.w)                                     \
    op[2 * (G)] = ov0;                                                  \
    op[2 * (G) + 1] = ov1;                                              \
  }

  LOADG(E, 0)
  LOADG(O, 1)
  for (int it = 0; it < 85; ++it) {
    int g = 3 * it;
    BODY(E, F, g)
    BODY(O, E, g + 1)
    BODY(F, O, g + 2)
  }
  // tail: group 255 (255 % 3 == 0 -> buffer E, loaded during g=253);
  // prefetch clamps to a redundant reload, harmless.
  BODY(E, F, NG - 1)
}

extern "C" void kernel_launch(void* const* d_in, const int* in_sizes, int n_in,
                              void* d_out, int out_size, void* d_ws, size_t ws_size,
                              hipStream_t stream) {
  const float* x = (const float*)d_in[0];        // (B, T, 1) fp32
  const float* op = (const float*)d_in[1];       // (B, 1, 1) fp32
  const float4* lstm = (const float4*)d_in[2];   // (B, T, 4) fp32
  int B = in_sizes[1];      // 4096
  int T = in_sizes[0] / B;  // 2048
  hipLaunchKernelGGL(fused_scan, dim3(B / ROWS), dim3(64), 0, stream,
                     x, op, lstm, (float*)d_out, B, T);
}

// Round 5
// 292.228 us; speedup vs baseline: 1.8750x; 1.8750x over previous
//
#include <hip/hip_runtime.h>

// R11b: speculative chunk scan + patch-up (R11 with macro fixes).
//
// Property used: each step either passes p through (identity) or resets it to
// a data-only constant (L1/V01/V11). Two trajectories over the same data merge
// permanently as soon as they produce equal values.
//
// Pass A spec_scan: one 64-step chunk per lane (B*T/64 = 131072 tasks).
//   chunk 0 seeded with true p0 (exact); chunks>=1 seeded with 0.0f
//   (speculative). Writes full trajectories to out. Streams at HBM roofline.
// Pass B fix_scan: one lane per row walks chunks 1..31 carrying the true
//   state; recomputes steps (bit-identical STEP) and compares with stored
//   out; on first bitwise match the stored suffix is exact -> jump to stored
//   chunk tail. First PF=16 steps of (lstm,x,out) per chunk are double-buffer
//   prefetched; beyond PF falls back to demand loads (rare).
//
// Step math verbatim from R4-R10 (bit-exact):
//   c1 = (p^s1m) >= L1f ; c2 = ((p^f2m) - a3f) >= a4f
//   p  = c2 ? (c1 ? V11 : V01) : (c1 ? L1 : p)

#define NCH 32  // T/64 chunks per row
#define PF 16   // prefetched steps per chunk in fix_scan

#define GLUE3(a, b, c) a##b##c

#define STEP(WV, XV)                                                      \
  {                                                                       \
    float4 wv_ = (WV); /* (m_lo, m_up, c_lo, c_up) */                     \
    float xv_ = (XV);                                                     \
    float a1_ = wv_.x * xv_, a2_ = wv_.x * wv_.z;                         \
    float L1v_ = a1_ + a2_;                                               \
    unsigned s1m_ = __float_as_uint(wv_.x) & 0x80000000u;                 \
    float L1f_ = __uint_as_float(__float_as_uint(L1v_) ^ s1m_);           \
    float a3_ = wv_.y * xv_, a4_ = wv_.y * wv_.w;                         \
    unsigned f2m_ = (__float_as_uint(wv_.y) & 0x80000000u) ^ 0x80000000u; \
    float a3f_ = __uint_as_float(__float_as_uint(a3_) ^ f2m_);            \
    float a4f_ = __uint_as_float(__float_as_uint(a4_) ^ f2m_);            \
    float V01_ = a3_ + a4_;                                               \
    float V11_ = (L1v_ + a3_) + a4_;                                      \
    unsigned pu_ = __float_as_uint(p);                                    \
    float pf_ = __uint_as_float(pu_ ^ s1m_);                              \
    bool c1_ = pf_ >= L1f_;                                               \
    float pp_ = __uint_as_float(pu_ ^ f2m_);                              \
    float qv_ = pp_ - a3f_;                                               \
    bool c2_ = qv_ >= a4f_;                                               \
    float i1_ = c1_ ? V11_ : V01_;                                        \
    float i2_ = c1_ ? L1v_ : p;                                           \
    p = c2_ ? i1_ : i2_;                                                  \
  }

// ======================= PASS A: speculative chunks =======================
__global__ __launch_bounds__(256, 2) void spec_scan(
    const float* __restrict__ x, const float* __restrict__ p0,
    const float4* __restrict__ lstm4, float* __restrict__ out,
    int B, int T) {
#pragma clang fp contract(off)
  const int g = blockIdx.x * 256 + threadIdx.x;  // task id
  const int row = g >> 5;
  const int c = g & 31;
  const size_t base = (size_t)row * T + (size_t)c * 64;
  const float4* lp = lstm4 + base;
  const float4* xp = reinterpret_cast<const float4*>(x + base);
  float4* op = reinterpret_cast<float4*>(out + base);
  float p = (c == 0) ? p0[row] : 0.0f;

#pragma unroll 4
  for (int q = 0; q < 16; ++q) {
    float4 L0 = lp[4 * q], L1 = lp[4 * q + 1];
    float4 L2 = lp[4 * q + 2], L3 = lp[4 * q + 3];
    float4 xq = xp[q];
    float4 ov;
    STEP(L0, xq.x) ov.x = p;
    STEP(L1, xq.y) ov.y = p;
    STEP(L2, xq.z) ov.z = p;
    STEP(L3, xq.w) ov.w = p;
    op[q] = ov;
  }
}

// ======================= PASS B: serial patch-up ==========================
__global__ __launch_bounds__(64, 1) void fix_scan(
    const float* __restrict__ x, const float* __restrict__ p0,
    const float4* __restrict__ lstm4, float* __restrict__ out,
    int B, int T) {
#pragma clang fp contract(off)
  const int row = blockIdx.x * 64 + threadIdx.x;
  if (row >= B) return;
  const size_t rbase = (size_t)row * T;
  const float4* lp = lstm4 + rbase;
  const float* xs = x + rbase;
  const float4* xp4 = reinterpret_cast<const float4*>(xs);
  float* outr = out + rbase;
  const float4* or4 = reinterpret_cast<const float4*>(outr);

  float4 LE0, LE1, LE2, LE3, LE4, LE5, LE6, LE7;
  float4 LE8, LE9, LE10, LE11, LE12, LE13, LE14, LE15;
  float4 XE0, XE1, XE2, XE3, OE0, OE1, OE2, OE3;
  float tailE;
  float4 LO0, LO1, LO2, LO3, LO4, LO5, LO6, LO7;
  float4 LO8, LO9, LO10, LO11, LO12, LO13, LO14, LO15;
  float4 XO0, XO1, XO2, XO3, OO0, OO1, OO2, OO3;
  float tailO;

#define LOADPF(S, CC)                                                   \
  {                                                                     \
    const float4* lb = lp + (size_t)(CC) * 64;                          \
    L##S##0 = lb[0];   L##S##1 = lb[1];   L##S##2 = lb[2];              \
    L##S##3 = lb[3];   L##S##4 = lb[4];   L##S##5 = lb[5];              \
    L##S##6 = lb[6];   L##S##7 = lb[7];   L##S##8 = lb[8];              \
    L##S##9 = lb[9];   L##S##10 = lb[10]; L##S##11 = lb[11];            \
    L##S##12 = lb[12]; L##S##13 = lb[13]; L##S##14 = lb[14];            \
    L##S##15 = lb[15];                                                  \
    const float4* xb = xp4 + (CC) * 16;                                 \
    X##S##0 = xb[0]; X##S##1 = xb[1]; X##S##2 = xb[2]; X##S##3 = xb[3]; \
    const float4* ob = or4 + (CC) * 16;                                 \
    O##S##0 = ob[0]; O##S##1 = ob[1]; O##S##2 = ob[2]; O##S##3 = ob[3]; \
    tail##S = outr[(CC) * 64 + 63];                                     \
  }

#define WSTEP(LV, XV, OV, I)                                            \
  if (!merged) {                                                        \
    STEP(LV, XV)                                                        \
    if (p == (OV)) merged = true;                                       \
    else outw[I] = p;                                                   \
  }

#define WALK(S, CC)                                                     \
  {                                                                     \
    const int cc = (CC);                                                \
    float* outw = outr + cc * 64;                                       \
    bool merged = false;                                                \
    WSTEP(GLUE3(L, S, 0),  GLUE3(X, S, 0).x, GLUE3(O, S, 0).x, 0)       \
    WSTEP(GLUE3(L, S, 1),  GLUE3(X, S, 0).y, GLUE3(O, S, 0).y, 1)       \
    WSTEP(GLUE3(L, S, 2),  GLUE3(X, S, 0).z, GLUE3(O, S, 0).z, 2)       \
    WSTEP(GLUE3(L, S, 3),  GLUE3(X, S, 0).w, GLUE3(O, S, 0).w, 3)       \
    WSTEP(GLUE3(L, S, 4),  GLUE3(X, S, 1).x, GLUE3(O, S, 1).x, 4)       \
    WSTEP(GLUE3(L, S, 5),  GLUE3(X, S, 1).y, GLUE3(O, S, 1).y, 5)       \
    WSTEP(GLUE3(L, S, 6),  GLUE3(X, S, 1).z, GLUE3(O, S, 1).z, 6)       \
    WSTEP(GLUE3(L, S, 7),  GLUE3(X, S, 1).w, GLUE3(O, S, 1).w, 7)       \
    WSTEP(GLUE3(L, S, 8),  GLUE3(X, S, 2).x, GLUE3(O, S, 2).x, 8)       \
    WSTEP(GLUE3(L, S, 9),  GLUE3(X, S, 2).y, GLUE3(O, S, 2).y, 9)       \
    WSTEP(GLUE3(L, S, 10), GLUE3(X, S, 2).z, GLUE3(O, S, 2).z, 10)      \
    WSTEP(GLUE3(L, S, 11), GLUE3(X, S, 2).w, GLUE3(O, S, 2).w, 11)      \
    WSTEP(GLUE3(L, S, 12), GLUE3(X, S, 3).x, GLUE3(O, S, 3).x, 12)      \
    WSTEP(GLUE3(L, S, 13), GLUE3(X, S, 3).y, GLUE3(O, S, 3).y, 13)      \
    WSTEP(GLUE3(L, S, 14), GLUE3(X, S, 3).z, GLUE3(O, S, 3).z, 14)      \
    WSTEP(GLUE3(L, S, 15), GLUE3(X, S, 3).w, GLUE3(O, S, 3).w, 15)      \
    if (!merged) {                                                      \
      for (int t = PF; t < 64; ++t) {                                   \
        STEP(lp[(size_t)cc * 64 + t], xs[cc * 64 + t])                  \
        float stored = outw[t];                                         \
        if (p == stored) { merged = true; break; }                      \
        outw[t] = p;                                                    \
      }                                                                 \
    }                                                                   \
    if (merged) p = tail##S;                                            \
  }

  float p = outr[63];  // end of chunk 0 (exact from pass A)
  LOADPF(E, 1)
  for (int cb = 1; cb < 31; cb += 2) {
    LOADPF(O, cb + 1)
    WALK(E, cb)
    LOADPF(E, cb + 2)  // cb <= 29 -> cb+2 <= 31
    WALK(O, cb + 1)
  }
  WALK(E, 31)
}

extern "C" void kernel_launch(void* const* d_in, const int* in_sizes, int n_in,
                              void* d_out, int out_size, void* d_ws, size_t ws_size,
                              hipStream_t stream) {
  const float* x = (const float*)d_in[0];        // (B, T, 1) fp32
  const float* op = (const float*)d_in[1];       // (B, 1, 1) fp32
  const float4* lstm = (const float4*)d_in[2];   // (B, T, 4) fp32
  int B = in_sizes[1];      // 4096
  int T = in_sizes[0] / B;  // 2048
  int tasks = B * (T / 64);
  hipLaunchKernelGGL(spec_scan, dim3(tasks / 256), dim3(256), 0, stream,
                     x, op, lstm, (float*)d_out, B, T);
  hipLaunchKernelGGL(fix_scan, dim3(B / 64), dim3(64), 0, stream,
                     x, op, lstm, (float*)d_out, B, T);
}